// Round 4
// baseline (15226.611 us; speedup 1.0000x reference)
//
#include <hip/hip_runtime.h>
#include <stdint.h>

// RTRBM CD-1: bit-exact replication of the JAX-CPU reference.
// Phase A: WV[t] = W @ v_t for all t in ONE launch (FMA, exact: v binary),
//          staged in the out_v region of d_out (overwritten later by phase C).
// Phase B: ONE persistent kernel, 250 blocks, internal grid barrier per t:
//          pre = (WV + U@r_lag) + bias -> sigmoid -> sample -> out_r.
// Phase C: all 256 visible steps in ONE launch, h read from out_r (FMA, exact).
// Sizes: V=784, H=500, T=256, B=256. RNG: threefry partitionable.
// Eigen MT blocking (AVX no-FMA jaxlib): kc=288. K=784 -> [288,288,208]; K=500 -> [288,212].
#define NV 784
#define NH 500
#define TT 256
#define BB 256

// ---------------- threefry2x32 (JAX PRNG), exact ----------------
__device__ __forceinline__ void tf2x32(uint32_t ks0, uint32_t ks1,
                                       uint32_t x0, uint32_t x1,
                                       uint32_t& y0, uint32_t& y1) {
  uint32_t ks2 = ks0 ^ ks1 ^ 0x1BD11BDAu;
  x0 += ks0; x1 += ks1;
#define TFROT(r) { x0 += x1; x1 = (x1 << (r)) | (x1 >> (32 - (r))); x1 ^= x0; }
  TFROT(13) TFROT(15) TFROT(26) TFROT(6)
  x0 += ks1; x1 += ks2 + 1u;
  TFROT(17) TFROT(29) TFROT(16) TFROT(24)
  x0 += ks2; x1 += ks0 + 2u;
  TFROT(13) TFROT(15) TFROT(26) TFROT(6)
  x0 += ks0; x1 += ks1 + 3u;
  TFROT(17) TFROT(29) TFROT(16) TFROT(24)
  x0 += ks1; x1 += ks2 + 4u;
  TFROT(13) TFROT(15) TFROT(26) TFROT(6)
  x0 += ks2; x1 += ks0 + 5u;
#undef TFROT
  y0 = x0; y1 = x1;
}

__device__ __forceinline__ float jax_uniform(uint32_t bits) {
#pragma clang fp contract(off)
  float f = __uint_as_float((bits >> 9) | 0x3F800000u);
  return f - 1.0f;
}

// PARTITIONABLE random_bits, 32-bit: bits[j] = y0 ^ y1 of threefry(key; 0, j)
__device__ __forceinline__ uint32_t draw_bits(uint32_t k0, uint32_t k1,
                                              uint32_t j) {
  uint32_t y0, y1;
  tf2x32(k0, k1, 0u, j, y0, y1);
  return y0 ^ y1;
}

// ---------------- XLA CPU exp (Cephes/Eigen poly, no FMA) ----------------
__device__ __forceinline__ float xla_expf(float x) {
#pragma clang fp contract(off)
  float xc = fminf(fmaxf(x, -88.3762626647949f), 88.3762626647950f);
  float fx = floorf(xc * 1.44269504088896341f + 0.5f);
  float tmp = 0.693359375f * fx;
  float z = -2.12194440e-4f * fx;
  float xr = xc - tmp;
  xr = xr - z;
  z = xr * xr;
  float y = xr * 1.9875691500e-4f + 1.3981999507e-3f;
  y = y * xr + 8.3334519073e-3f;
  y = y * xr + 4.1665795894e-2f;
  y = y * xr + 1.6666665459e-1f;
  y = y * xr + 5.0000001201e-1f;
  y = y * z + xr;
  y = 1.0f + y;
  int e = (int)fx;
  float pow2 = __int_as_float((uint32_t)(e + 127) << 23);
  return y * pow2;
}

__device__ __forceinline__ float xla_sigmoid(float x) {
#pragma clang fp contract(off)
  float e = xla_expf(-x);
  float d = 1.0f + e;
  return 1.0f / d;
}

// ---------------- key derivation (PARTITIONABLE split) ----------------
__global__ void init_keys(uint32_t* __restrict__ keys /* [256][4] */) {
  int t = threadIdx.x;
  if (t >= TT) return;
  uint32_t kt0, kt1;
  tf2x32(0u, 123u, 0u, (uint32_t)t, kt0, kt1);
  uint32_t a0, a1, b0, b1;
  tf2x32(kt0, kt1, 0u, 0u, a0, a1);  // k1
  tf2x32(kt0, kt1, 0u, 1u, b0, b1);  // k2
  keys[4 * t + 0] = a0;
  keys[4 * t + 1] = a1;
  keys[4 * t + 2] = b0;
  keys[4 * t + 3] = b1;
}

// ---------------- W transpose: WT[i][k] = W[k][i] ----------------
__global__ __launch_bounds__(256) void wt_kernel(const float* __restrict__ W,
                                                 float* __restrict__ WT) {
  const int i = blockIdx.x;           // 0..783
  for (int k = threadIdx.x; k < NH; k += 256)
    WT[(size_t)i * NH + k] = W[(size_t)k * NV + i];
}

// ---------------- Phase A: WV[t][h][b] = (W @ v_t)[h][b] ----------------
// fmaf(w, x, s) == s + w*x bit-exactly because x in {0,1} (w*x exact).
#define HT_A 25   // 500/25 = 20 blocks per t
__global__ __launch_bounds__(256) void wv_gemm(
    const float* __restrict__ v, const float* __restrict__ W,
    float* __restrict__ wv) {
#pragma clang fp contract(off)
  const int b = threadIdx.x;
  const int h0 = blockIdx.x * HT_A;
  const int t = blockIdx.y;
  const float* vcol = v + (size_t)t * BB + b;   // element k: vcol[k * TT*BB]

  float acc[HT_A];
#pragma unroll
  for (int r = 0; r < HT_A; ++r) acc[r] = 0.0f;

  const int pb[4] = {0, 288, 576, 784};   // kc=288 panels
#pragma unroll 1
  for (int p = 0; p < 3; ++p) {
    float ps[HT_A];
#pragma unroll
    for (int r = 0; r < HT_A; ++r) ps[r] = 0.0f;
    const int k0 = pb[p], k1 = pb[p + 1];
#pragma unroll 4
    for (int k = k0; k < k1; ++k) {
      float x = vcol[(size_t)k * (TT * BB)];
#pragma unroll
      for (int r = 0; r < HT_A; ++r)
        ps[r] = __builtin_fmaf(W[(size_t)(h0 + r) * NV + k], x, ps[r]);
    }
#pragma unroll
    for (int r = 0; r < HT_A; ++r) acc[r] = acc[r] + ps[r];
  }
#pragma unroll
  for (int r = 0; r < HT_A; ++r)
    wv[((size_t)t * NH + (h0 + r)) * BB + b] = acc[r];
}

// ---------------- Phase B: persistent serial hidden sweep ----------------
#define HT_B 2
#define NBLK_B (NH / HT_B)   // 250 blocks <= 256 CUs -> co-resident
__global__ __launch_bounds__(256) void hidden_persist(
    const float* __restrict__ wv, const float* __restrict__ U,
    const float* __restrict__ b_h, const float* __restrict__ b_init,
    const uint32_t* __restrict__ keys, float* __restrict__ rbuf0,
    float* __restrict__ rbuf1, float* __restrict__ out_r,
    uint32_t* __restrict__ bar) {
#pragma clang fp contract(off)
  const int b = threadIdx.x;
  const int h0 = blockIdx.x * HT_B;

  for (int t = 0; t < TT; ++t) {
    const float* r_old = (t & 1) ? rbuf1 : rbuf0;
    float* r_new = (t & 1) ? rbuf0 : rbuf1;

    // U @ r_lag : mul-then-add (no FMA — r arbitrary), kc=288 panels
    float accu[HT_B];
#pragma unroll
    for (int r = 0; r < HT_B; ++r) accu[r] = 0.0f;
    const int pb[3] = {0, 288, 500};
#pragma unroll 1
    for (int p = 0; p < 2; ++p) {
      float ps[HT_B];
#pragma unroll
      for (int r = 0; r < HT_B; ++r) ps[r] = 0.0f;
      const int k0 = pb[p], k1 = pb[p + 1];
#pragma unroll 8
      for (int k = k0; k < k1; ++k) {
        float rr = r_old[k * BB + b];
#pragma unroll
        for (int r = 0; r < HT_B; ++r) {
          float uu = U[(size_t)(h0 + r) * NH + k];
          ps[r] = ps[r] + uu * rr;
        }
      }
#pragma unroll
      for (int r = 0; r < HT_B; ++r) accu[r] = accu[r] + ps[r];
    }

    const uint32_t key0 = keys[4 * t + 0], key1 = keys[4 * t + 1];
#pragma unroll
    for (int r = 0; r < HT_B; ++r) {
      const int h = h0 + r;
      float bias = (t == 0) ? b_init[h] : b_h[h];
      float wvv = wv[((size_t)t * NH + h) * BB + b];
      float pre = (wvv + accu[r]) + bias;
      float p = xla_sigmoid(pre);
      uint32_t j = (uint32_t)(h * BB + b);
      float u = jax_uniform(draw_bits(key0, key1, j));
      r_new[h * BB + b] = p;
      out_r[(size_t)h * (TT * BB) + (size_t)t * BB + b] = (u < p) ? 1.0f : 0.0f;
    }

    // grid barrier (monotone counter; 256*250 = 64000 fits u32)
    __syncthreads();
    if (threadIdx.x == 0) {
      __threadfence();   // release our r_new writes device-wide
      __hip_atomic_fetch_add(bar, 1u, __ATOMIC_ACQ_REL, __HIP_MEMORY_SCOPE_AGENT);
      const uint32_t target = (uint32_t)(t + 1) * (uint32_t)NBLK_B;
      while (__hip_atomic_load(bar, __ATOMIC_ACQUIRE, __HIP_MEMORY_SCOPE_AGENT) < target)
        __builtin_amdgcn_s_sleep(2);
      __threadfence();   // acquire: invalidate L1/L2-stale before reading r_new
    }
    __syncthreads();
  }
}

// ---------------- Phase C: all visible steps; h read from out_r ----------------
// fmaf(w, h, s) == s + w*h bit-exactly because h in {0,1}.
#define IT_C 16   // 784/16 = 49 i-tiles
__global__ __launch_bounds__(256) void visible_big(
    const float* __restrict__ WT, const float* __restrict__ b_v,
    const uint32_t* __restrict__ keys, const float* __restrict__ hplane,
    float* __restrict__ out_v) {
#pragma clang fp contract(off)
  const int b = threadIdx.x;
  const int i0 = blockIdx.x * IT_C;
  const int t = blockIdx.y;
  const float* hcol = hplane + (size_t)t * BB + b;  // element k: hcol[k * TT*BB]

  float acc[IT_C];
#pragma unroll
  for (int r = 0; r < IT_C; ++r) acc[r] = 0.0f;

  const int pb[3] = {0, 288, 500};
#pragma unroll 1
  for (int p = 0; p < 2; ++p) {
    float ps[IT_C];
#pragma unroll
    for (int r = 0; r < IT_C; ++r) ps[r] = 0.0f;
    const int k0 = pb[p], k1 = pb[p + 1];
#pragma unroll 4
    for (int k = k0; k < k1; ++k) {
      float hh = hcol[(size_t)k * (TT * BB)];
#pragma unroll
      for (int r = 0; r < IT_C; ++r)
        ps[r] = __builtin_fmaf(WT[(size_t)(i0 + r) * NH + k], hh, ps[r]);
    }
#pragma unroll
    for (int r = 0; r < IT_C; ++r) acc[r] = acc[r] + ps[r];
  }

  const uint32_t key0 = keys[4 * t + 2], key1 = keys[4 * t + 3];
#pragma unroll
  for (int r = 0; r < IT_C; ++r) {
    const int i = i0 + r;
    float pre = acc[r] + b_v[i];
    float p = xla_sigmoid(pre);
    uint32_t j = (uint32_t)(i * BB + b);
    float u = jax_uniform(draw_bits(key0, key1, j));
    out_v[(size_t)i * (TT * BB) + (size_t)t * BB + b] = (u < p) ? 1.0f : 0.0f;
  }
}

extern "C" void kernel_launch(void* const* d_in, const int* in_sizes, int n_in,
                              void* d_out, int out_size, void* d_ws, size_t ws_size,
                              hipStream_t stream) {
  const float* v      = (const float*)d_in[0];
  const float* W      = (const float*)d_in[1];
  const float* U      = (const float*)d_in[2];
  const float* b_h    = (const float*)d_in[3];
  const float* b_v    = (const float*)d_in[4];
  const float* b_init = (const float*)d_in[5];

  float* out_v = (float*)d_out;                       // (784,256,256)
  float* out_r = out_v + (size_t)NV * TT * BB;        // (500,256,256)

  // WV for all t lives in the out_v region (131 MB <= 205 MB); phase C
  // overwrites out_v afterwards and never reads WV.
  float* wv = out_v;

  // ws layout: r0, r1, WT, keys, bar  (~2.6 MB total)
  float* r0 = (float*)d_ws;
  float* r1 = r0 + (size_t)NH * BB;
  float* WT = r1 + (size_t)NH * BB;
  uint32_t* keys = (uint32_t*)(WT + (size_t)NV * NH);
  uint32_t* bar = keys + TT * 4;

  hipMemsetAsync(r0, 0, (size_t)NH * BB * sizeof(float), stream);  // r_lag(0)=0
  hipMemsetAsync(bar, 0, sizeof(uint32_t), stream);
  init_keys<<<1, 256, 0, stream>>>(keys);
  wt_kernel<<<NV, 256, 0, stream>>>(W, WT);

  dim3 gA(NH / HT_A, TT);
  wv_gemm<<<gA, 256, 0, stream>>>(v, W, wv);

  hidden_persist<<<NBLK_B, 256, 0, stream>>>(wv, U, b_h, b_init, keys,
                                             r0, r1, out_r, bar);

  dim3 gC(NV / IT_C, TT);
  visible_big<<<gC, 256, 0, stream>>>(WT, b_v, keys, out_r, out_v);
}

// Round 5
// 12351.318 us; speedup vs baseline: 1.2328x; 1.2328x over previous
//
#include <hip/hip_runtime.h>
#include <stdint.h>

// RTRBM CD-1: bit-exact replication of the JAX-CPU reference.
// Phase A: WV[t] = W @ v_t, all t, one launch (FMA exact: v binary), into out_v region.
// Phase B: ONE persistent kernel, 250 blocks x 512 threads:
//          2-way k-panel parallelism (Eigen kc=288 boundary), LDS combine,
//          bucketed grid barrier per t.
// Phase C: all visible steps, one launch, h from out_r (FMA exact: h binary).
// Sizes: V=784, H=500, T=256, B=256. RNG: threefry partitionable.
#define NV 784
#define NH 500
#define TT 256
#define BB 256
#define NBLK_B 250
#define NBUCK 16   // barrier arrival buckets, 128B apart

// ---------------- threefry2x32 (JAX PRNG), exact ----------------
__device__ __forceinline__ void tf2x32(uint32_t ks0, uint32_t ks1,
                                       uint32_t x0, uint32_t x1,
                                       uint32_t& y0, uint32_t& y1) {
  uint32_t ks2 = ks0 ^ ks1 ^ 0x1BD11BDAu;
  x0 += ks0; x1 += ks1;
#define TFROT(r) { x0 += x1; x1 = (x1 << (r)) | (x1 >> (32 - (r))); x1 ^= x0; }
  TFROT(13) TFROT(15) TFROT(26) TFROT(6)
  x0 += ks1; x1 += ks2 + 1u;
  TFROT(17) TFROT(29) TFROT(16) TFROT(24)
  x0 += ks2; x1 += ks0 + 2u;
  TFROT(13) TFROT(15) TFROT(26) TFROT(6)
  x0 += ks0; x1 += ks1 + 3u;
  TFROT(17) TFROT(29) TFROT(16) TFROT(24)
  x0 += ks1; x1 += ks2 + 4u;
  TFROT(13) TFROT(15) TFROT(26) TFROT(6)
  x0 += ks2; x1 += ks0 + 5u;
#undef TFROT
  y0 = x0; y1 = x1;
}

__device__ __forceinline__ float jax_uniform(uint32_t bits) {
#pragma clang fp contract(off)
  float f = __uint_as_float((bits >> 9) | 0x3F800000u);
  return f - 1.0f;
}

// PARTITIONABLE random_bits, 32-bit: bits[j] = y0 ^ y1 of threefry(key; 0, j)
__device__ __forceinline__ uint32_t draw_bits(uint32_t k0, uint32_t k1,
                                              uint32_t j) {
  uint32_t y0, y1;
  tf2x32(k0, k1, 0u, j, y0, y1);
  return y0 ^ y1;
}

// ---------------- XLA CPU exp (Cephes/Eigen poly, no FMA) ----------------
__device__ __forceinline__ float xla_expf(float x) {
#pragma clang fp contract(off)
  float xc = fminf(fmaxf(x, -88.3762626647949f), 88.3762626647950f);
  float fx = floorf(xc * 1.44269504088896341f + 0.5f);
  float tmp = 0.693359375f * fx;
  float z = -2.12194440e-4f * fx;
  float xr = xc - tmp;
  xr = xr - z;
  z = xr * xr;
  float y = xr * 1.9875691500e-4f + 1.3981999507e-3f;
  y = y * xr + 8.3334519073e-3f;
  y = y * xr + 4.1665795894e-2f;
  y = y * xr + 1.6666665459e-1f;
  y = y * xr + 5.0000001201e-1f;
  y = y * z + xr;
  y = 1.0f + y;
  int e = (int)fx;
  float pow2 = __int_as_float((uint32_t)(e + 127) << 23);
  return y * pow2;
}

__device__ __forceinline__ float xla_sigmoid(float x) {
#pragma clang fp contract(off)
  float e = xla_expf(-x);
  float d = 1.0f + e;
  return 1.0f / d;
}

// ---------------- key derivation (PARTITIONABLE split) ----------------
__global__ void init_keys(uint32_t* __restrict__ keys /* [256][4] */) {
  int t = threadIdx.x;
  if (t >= TT) return;
  uint32_t kt0, kt1;
  tf2x32(0u, 123u, 0u, (uint32_t)t, kt0, kt1);
  uint32_t a0, a1, b0, b1;
  tf2x32(kt0, kt1, 0u, 0u, a0, a1);  // k1
  tf2x32(kt0, kt1, 0u, 1u, b0, b1);  // k2
  keys[4 * t + 0] = a0;
  keys[4 * t + 1] = a1;
  keys[4 * t + 2] = b0;
  keys[4 * t + 3] = b1;
}

// ---------------- W transpose: WT[i][k] = W[k][i] ----------------
__global__ __launch_bounds__(256) void wt_kernel(const float* __restrict__ W,
                                                 float* __restrict__ WT) {
  const int i = blockIdx.x;           // 0..783
  for (int k = threadIdx.x; k < NH; k += 256)
    WT[(size_t)i * NH + k] = W[(size_t)k * NV + i];
}

// ---------------- Phase A: WV[t][h][b] = (W @ v_t)[h][b] ----------------
// fmaf(w, x, s) == s + w*x bit-exactly because x in {0,1} (w*x exact).
#define HT_A 25   // 500/25 = 20 blocks per t
__global__ __launch_bounds__(256) void wv_gemm(
    const float* __restrict__ v, const float* __restrict__ W,
    float* __restrict__ wv) {
#pragma clang fp contract(off)
  const int b = threadIdx.x;
  const int h0 = blockIdx.x * HT_A;
  const int t = blockIdx.y;
  const float* vcol = v + (size_t)t * BB + b;   // element k: vcol[k * TT*BB]

  float acc[HT_A];
#pragma unroll
  for (int r = 0; r < HT_A; ++r) acc[r] = 0.0f;

  const int pb[4] = {0, 288, 576, 784};   // kc=288 panels
#pragma unroll 1
  for (int p = 0; p < 3; ++p) {
    float ps[HT_A];
#pragma unroll
    for (int r = 0; r < HT_A; ++r) ps[r] = 0.0f;
    const int k0 = pb[p], k1 = pb[p + 1];
#pragma unroll 4
    for (int k = k0; k < k1; ++k) {
      float x = vcol[(size_t)k * (TT * BB)];
#pragma unroll
      for (int r = 0; r < HT_A; ++r)
        ps[r] = __builtin_fmaf(W[(size_t)(h0 + r) * NV + k], x, ps[r]);
    }
#pragma unroll
    for (int r = 0; r < HT_A; ++r) acc[r] = acc[r] + ps[r];
  }
#pragma unroll
  for (int r = 0; r < HT_A; ++r)
    wv[((size_t)t * NH + (h0 + r)) * BB + b] = acc[r];
}

// ---------------- Phase B: persistent serial hidden sweep, 2-panel split ----------------
// Block: 512 threads = {panel 0: tid 0..255, panel 1: tid 256..511}; 2 h-rows/block.
// accu = ps0 + ps1 is bit-identical to the reference's (0+ps0)+ps1 panel order.
__global__ __launch_bounds__(512) void hidden_persist(
    const float* __restrict__ wv, const float* __restrict__ U,
    const float* __restrict__ b_h, const float* __restrict__ b_init,
    const uint32_t* __restrict__ keys, float* __restrict__ rbuf0,
    float* __restrict__ rbuf1, float* __restrict__ out_r,
    uint32_t* __restrict__ bar) {
#pragma clang fp contract(off)
  const int tid = threadIdx.x;
  const int b = tid & 255;
  const int p = tid >> 8;           // k-panel: 0 -> [0,288), 1 -> [288,500)
  const int h0 = blockIdx.x * 2;
  __shared__ float ps_lds[2][BB];

  const int k0 = p ? 288 : 0;
  const int k1 = p ? NH : 288;
  const float* __restrict__ U0 = U + (size_t)h0 * NH;
  const float* __restrict__ U1 = U + (size_t)(h0 + 1) * NH;

  for (int t = 0; t < TT; ++t) {
    const float* __restrict__ r_old = (t & 1) ? rbuf1 : rbuf0;
    float* __restrict__ r_new = (t & 1) ? rbuf0 : rbuf1;

    // prefetch wv (epilogue operand) so it hides under the dot loop
    float wv0 = 0.0f, wv1 = 0.0f;
    if (p == 0) {
      wv0 = wv[((size_t)t * NH + h0) * BB + b];
      wv1 = wv[((size_t)t * NH + h0 + 1) * BB + b];
    }

    // panel-partial dots, mul-then-add (no FMA: r arbitrary), ascending k
    float ps0 = 0.0f, ps1 = 0.0f;
#pragma unroll 8
    for (int k = k0; k < k1; ++k) {
      float rr = r_old[k * BB + b];
      ps0 = ps0 + U0[k] * rr;   // U0[k], U1[k] lane-uniform -> scalar K$ loads
      ps1 = ps1 + U1[k] * rr;
    }
    if (p == 1) { ps_lds[0][b] = ps0; ps_lds[1][b] = ps1; }
    __syncthreads();

    if (p == 0) {
      const uint32_t key0 = keys[4 * t + 0], key1 = keys[4 * t + 1];
      float acc0 = ps0 + ps_lds[0][b];     // == (0+ps0)+ps1 of the reference
      float acc1 = ps1 + ps_lds[1][b];
      float bias0 = (t == 0) ? b_init[h0] : b_h[h0];
      float bias1 = (t == 0) ? b_init[h0 + 1] : b_h[h0 + 1];
      float pre0 = (wv0 + acc0) + bias0;
      float pre1 = (wv1 + acc1) + bias1;
      float pp0 = xla_sigmoid(pre0);
      float pp1 = xla_sigmoid(pre1);
      r_new[h0 * BB + b] = pp0;
      r_new[(h0 + 1) * BB + b] = pp1;
      uint32_t j0 = (uint32_t)(h0 * BB + b);
      uint32_t j1 = (uint32_t)((h0 + 1) * BB + b);
      float u0 = jax_uniform(draw_bits(key0, key1, j0));
      float u1 = jax_uniform(draw_bits(key0, key1, j1));
      out_r[(size_t)h0 * (TT * BB) + (size_t)t * BB + b] = (u0 < pp0) ? 1.0f : 0.0f;
      out_r[(size_t)(h0 + 1) * (TT * BB) + (size_t)t * BB + b] = (u1 < pp1) ? 1.0f : 0.0f;
    }

    // ---- bucketed grid barrier ----
    __syncthreads();
    if (tid == 0) {
      __threadfence();   // release r_new device-wide
      const int bk = blockIdx.x & (NBUCK - 1);
      // 250 = 16*15 + 10: buckets 0..9 have 16 blocks, 10..15 have 15
      const uint32_t bsize = (bk < (NBLK_B & (NBUCK - 1))) ? (NBLK_B / NBUCK + 1)
                                                           : (NBLK_B / NBUCK);
      uint32_t old = __hip_atomic_fetch_add(&bar[bk * 32], 1u,
                                            __ATOMIC_ACQ_REL, __HIP_MEMORY_SCOPE_AGENT);
      if ((old % bsize) == bsize - 1u)
        __hip_atomic_fetch_add(&bar[NBUCK * 32], bsize,
                               __ATOMIC_ACQ_REL, __HIP_MEMORY_SCOPE_AGENT);
      const uint32_t target = (uint32_t)(t + 1) * (uint32_t)NBLK_B;
      while (__hip_atomic_load(&bar[NBUCK * 32],
                               __ATOMIC_ACQUIRE, __HIP_MEMORY_SCOPE_AGENT) < target)
        __builtin_amdgcn_s_sleep(2);
      __threadfence();   // acquire side
    }
    __syncthreads();
  }
}

// ---------------- Phase C: all visible steps; h read from out_r ----------------
// fmaf(w, h, s) == s + w*h bit-exactly because h in {0,1}.
#define IT_C 16   // 784/16 = 49 i-tiles
__global__ __launch_bounds__(256) void visible_big(
    const float* __restrict__ WT, const float* __restrict__ b_v,
    const uint32_t* __restrict__ keys, const float* __restrict__ hplane,
    float* __restrict__ out_v) {
#pragma clang fp contract(off)
  const int b = threadIdx.x;
  const int i0 = blockIdx.x * IT_C;
  const int t = blockIdx.y;
  const float* hcol = hplane + (size_t)t * BB + b;  // element k: hcol[k * TT*BB]

  float acc[IT_C];
#pragma unroll
  for (int r = 0; r < IT_C; ++r) acc[r] = 0.0f;

  const int pb[3] = {0, 288, 500};
#pragma unroll 1
  for (int p = 0; p < 2; ++p) {
    float ps[IT_C];
#pragma unroll
    for (int r = 0; r < IT_C; ++r) ps[r] = 0.0f;
    const int k0 = pb[p], k1 = pb[p + 1];
#pragma unroll 4
    for (int k = k0; k < k1; ++k) {
      float hh = hcol[(size_t)k * (TT * BB)];
#pragma unroll
      for (int r = 0; r < IT_C; ++r)
        ps[r] = __builtin_fmaf(WT[(size_t)(i0 + r) * NH + k], hh, ps[r]);
    }
#pragma unroll
    for (int r = 0; r < IT_C; ++r) acc[r] = acc[r] + ps[r];
  }

  const uint32_t key0 = keys[4 * t + 2], key1 = keys[4 * t + 3];
#pragma unroll
  for (int r = 0; r < IT_C; ++r) {
    const int i = i0 + r;
    float pre = acc[r] + b_v[i];
    float p = xla_sigmoid(pre);
    uint32_t j = (uint32_t)(i * BB + b);
    float u = jax_uniform(draw_bits(key0, key1, j));
    out_v[(size_t)i * (TT * BB) + (size_t)t * BB + b] = (u < p) ? 1.0f : 0.0f;
  }
}

extern "C" void kernel_launch(void* const* d_in, const int* in_sizes, int n_in,
                              void* d_out, int out_size, void* d_ws, size_t ws_size,
                              hipStream_t stream) {
  const float* v      = (const float*)d_in[0];
  const float* W      = (const float*)d_in[1];
  const float* U      = (const float*)d_in[2];
  const float* b_h    = (const float*)d_in[3];
  const float* b_v    = (const float*)d_in[4];
  const float* b_init = (const float*)d_in[5];

  float* out_v = (float*)d_out;                       // (784,256,256)
  float* out_r = out_v + (size_t)NV * TT * BB;        // (500,256,256)

  // WV for all t lives in the out_v region (131 MB <= 205 MB); phase C
  // overwrites out_v afterwards and never reads WV.
  float* wv = out_v;

  // ws layout: r0, r1, WT, keys, bar
  float* r0 = (float*)d_ws;
  float* r1 = r0 + (size_t)NH * BB;
  float* WT = r1 + (size_t)NH * BB;
  uint32_t* keys = (uint32_t*)(WT + (size_t)NV * NH);
  uint32_t* bar = keys + TT * 4;   // (NBUCK+1)*32 u32, 128B-spaced counters

  hipMemsetAsync(r0, 0, (size_t)NH * BB * sizeof(float), stream);  // r_lag(0)=0
  hipMemsetAsync(bar, 0, (NBUCK + 1) * 32 * sizeof(uint32_t), stream);
  init_keys<<<1, 256, 0, stream>>>(keys);
  wt_kernel<<<NV, 256, 0, stream>>>(W, WT);

  dim3 gA(NH / HT_A, TT);
  wv_gemm<<<gA, 256, 0, stream>>>(v, W, wv);

  hidden_persist<<<NBLK_B, 512, 0, stream>>>(wv, U, b_h, b_init, keys,
                                             r0, r1, out_r, bar);

  dim3 gC(NV / IT_C, TT);
  visible_big<<<gC, 256, 0, stream>>>(WT, b_v, keys, out_r, out_v);
}

// Round 6
// 9579.855 us; speedup vs baseline: 1.5894x; 1.2893x over previous
//
#include <hip/hip_runtime.h>
#include <stdint.h>

// RTRBM CD-1: bit-exact replication of the JAX-CPU reference.
// Phase A: WV[t] = W @ v_t, all t, one launch (FMA exact: v binary), into out_v region.
// Phase B: ONE persistent kernel, 250 blocks x 512 threads.
//          U rows + keys staged in LDS (immune to per-t L2 invalidation);
//          dot software-pipelined in 32-wide register chunks; RNG on the p=1 half;
//          relaxed-spin bucketed grid barrier with single release/acquire fences.
// Phase C: all visible steps, one launch, h from out_r (FMA exact: h binary).
// Sizes: V=784, H=500, T=256, B=256. RNG: threefry partitionable.
// Eigen MT blocking (AVX no-FMA jaxlib): kc=288. K=784 -> [288,288,208]; K=500 -> [288,212].
#define NV 784
#define NH 500
#define TT 256
#define BB 256
#define NBLK_B 250
#define NBUCK 16      // barrier arrival buckets, 128B apart
#define RPAD 512      // r buffers padded to 512 rows (pad rows zero)

// ---------------- threefry2x32 (JAX PRNG), exact ----------------
__device__ __forceinline__ void tf2x32(uint32_t ks0, uint32_t ks1,
                                       uint32_t x0, uint32_t x1,
                                       uint32_t& y0, uint32_t& y1) {
  uint32_t ks2 = ks0 ^ ks1 ^ 0x1BD11BDAu;
  x0 += ks0; x1 += ks1;
#define TFROT(r) { x0 += x1; x1 = (x1 << (r)) | (x1 >> (32 - (r))); x1 ^= x0; }
  TFROT(13) TFROT(15) TFROT(26) TFROT(6)
  x0 += ks1; x1 += ks2 + 1u;
  TFROT(17) TFROT(29) TFROT(16) TFROT(24)
  x0 += ks2; x1 += ks0 + 2u;
  TFROT(13) TFROT(15) TFROT(26) TFROT(6)
  x0 += ks0; x1 += ks1 + 3u;
  TFROT(17) TFROT(29) TFROT(16) TFROT(24)
  x0 += ks1; x1 += ks2 + 4u;
  TFROT(13) TFROT(15) TFROT(26) TFROT(6)
  x0 += ks2; x1 += ks0 + 5u;
#undef TFROT
  y0 = x0; y1 = x1;
}

__device__ __forceinline__ float jax_uniform(uint32_t bits) {
#pragma clang fp contract(off)
  float f = __uint_as_float((bits >> 9) | 0x3F800000u);
  return f - 1.0f;
}

// PARTITIONABLE random_bits, 32-bit: bits[j] = y0 ^ y1 of threefry(key; 0, j)
__device__ __forceinline__ uint32_t draw_bits(uint32_t k0, uint32_t k1,
                                              uint32_t j) {
  uint32_t y0, y1;
  tf2x32(k0, k1, 0u, j, y0, y1);
  return y0 ^ y1;
}

// ---------------- XLA CPU exp (Cephes/Eigen poly, no FMA) ----------------
__device__ __forceinline__ float xla_expf(float x) {
#pragma clang fp contract(off)
  float xc = fminf(fmaxf(x, -88.3762626647949f), 88.3762626647950f);
  float fx = floorf(xc * 1.44269504088896341f + 0.5f);
  float tmp = 0.693359375f * fx;
  float z = -2.12194440e-4f * fx;
  float xr = xc - tmp;
  xr = xr - z;
  z = xr * xr;
  float y = xr * 1.9875691500e-4f + 1.3981999507e-3f;
  y = y * xr + 8.3334519073e-3f;
  y = y * xr + 4.1665795894e-2f;
  y = y * xr + 1.6666665459e-1f;
  y = y * xr + 5.0000001201e-1f;
  y = y * z + xr;
  y = 1.0f + y;
  int e = (int)fx;
  float pow2 = __int_as_float((uint32_t)(e + 127) << 23);
  return y * pow2;
}

__device__ __forceinline__ float xla_sigmoid(float x) {
#pragma clang fp contract(off)
  float e = xla_expf(-x);
  float d = 1.0f + e;
  return 1.0f / d;
}

// ---------------- key derivation (PARTITIONABLE split) ----------------
__global__ void init_keys(uint32_t* __restrict__ keys /* [256][4] */) {
  int t = threadIdx.x;
  if (t >= TT) return;
  uint32_t kt0, kt1;
  tf2x32(0u, 123u, 0u, (uint32_t)t, kt0, kt1);
  uint32_t a0, a1, b0, b1;
  tf2x32(kt0, kt1, 0u, 0u, a0, a1);  // k1
  tf2x32(kt0, kt1, 0u, 1u, b0, b1);  // k2
  keys[4 * t + 0] = a0;
  keys[4 * t + 1] = a1;
  keys[4 * t + 2] = b0;
  keys[4 * t + 3] = b1;
}

// ---------------- W transpose: WT[i][k] = W[k][i] ----------------
__global__ __launch_bounds__(256) void wt_kernel(const float* __restrict__ W,
                                                 float* __restrict__ WT) {
  const int i = blockIdx.x;           // 0..783
  for (int k = threadIdx.x; k < NH; k += 256)
    WT[(size_t)i * NH + k] = W[(size_t)k * NV + i];
}

// ---------------- Phase A: WV[t][h][b] = (W @ v_t)[h][b] ----------------
// fmaf(w, x, s) == s + w*x bit-exactly because x in {0,1} (w*x exact).
#define HT_A 25   // 500/25 = 20 blocks per t
__global__ __launch_bounds__(256) void wv_gemm(
    const float* __restrict__ v, const float* __restrict__ W,
    float* __restrict__ wv) {
#pragma clang fp contract(off)
  const int b = threadIdx.x;
  const int h0 = blockIdx.x * HT_A;
  const int t = blockIdx.y;
  const float* vcol = v + (size_t)t * BB + b;   // element k: vcol[k * TT*BB]

  float acc[HT_A];
#pragma unroll
  for (int r = 0; r < HT_A; ++r) acc[r] = 0.0f;

  const int pb[4] = {0, 288, 576, 784};   // kc=288 panels
#pragma unroll 1
  for (int p = 0; p < 3; ++p) {
    float ps[HT_A];
#pragma unroll
    for (int r = 0; r < HT_A; ++r) ps[r] = 0.0f;
    const int k0 = pb[p], k1 = pb[p + 1];
#pragma unroll 8
    for (int k = k0; k < k1; ++k) {
      float x = vcol[(size_t)k * (TT * BB)];
#pragma unroll
      for (int r = 0; r < HT_A; ++r)
        ps[r] = __builtin_fmaf(W[(size_t)(h0 + r) * NV + k], x, ps[r]);
    }
#pragma unroll
    for (int r = 0; r < HT_A; ++r) acc[r] = acc[r] + ps[r];
  }
#pragma unroll
  for (int r = 0; r < HT_A; ++r)
    wv[((size_t)t * NH + (h0 + r)) * BB + b] = acc[r];
}

// ---------------- Phase B: persistent serial hidden sweep ----------------
// Software-pipelined panel dot: NC chunks of 32 k, double-buffered registers.
// All array indices compile-time (full unroll) so buffers stay in VGPRs.
// Summation order: strict ascending k within the panel (bit-exact; pad terms
// at the chain end add +0.0f exactly since U-pad = 0 and r-pad = 0).
template <int NC>
__device__ __forceinline__ void panel_dot(
    const float* __restrict__ r_old, const int kbase, const int b,
    const float (*__restrict__ Ul2)[2], float& out0, float& out1) {
#pragma clang fp contract(off)
  float cur[32], nxt[32];
#pragma unroll
  for (int i = 0; i < 32; ++i) cur[i] = r_old[(kbase + i) * BB + b];
  float a0 = 0.0f, a1 = 0.0f;
#pragma unroll
  for (int c = 0; c < NC; ++c) {
    if (c + 1 < NC) {
#pragma unroll
      for (int i = 0; i < 32; ++i)
        nxt[i] = r_old[(kbase + (c + 1) * 32 + i) * BB + b];
    }
#pragma unroll
    for (int i = 0; i < 32; ++i) {
      const int k = kbase + c * 32 + i;
      float u0 = Ul2[k][0];
      float u1 = Ul2[k][1];
      a0 = a0 + u0 * cur[i];   // mul-then-add (no FMA): r arbitrary
      a1 = a1 + u1 * cur[i];
    }
    if (c + 1 < NC) {
#pragma unroll
      for (int i = 0; i < 32; ++i) cur[i] = nxt[i];
    }
  }
  out0 = a0;
  out1 = a1;
}

__global__ __launch_bounds__(512) void hidden_persist(
    const float* __restrict__ wv, const float* __restrict__ U,
    const float* __restrict__ b_h, const float* __restrict__ b_init,
    const uint32_t* __restrict__ keys, float* __restrict__ rbuf0,
    float* __restrict__ rbuf1, float* __restrict__ out_r,
    uint32_t* __restrict__ bar) {
#pragma clang fp contract(off)
  const int tid = threadIdx.x;
  const int b = tid & 255;
  const int p = tid >> 8;           // k-panel: 0 -> [0,288), 1 -> [288,500)+pad
  const int h0 = blockIdx.x * 2;

  __shared__ float Ul2[RPAD][2];          // U rows interleaved, zero-padded
  __shared__ float ps_lds[2][BB];
  __shared__ float u_lds[2][BB];
  __shared__ uint32_t keyl[2 * TT];       // hidden keys (k1 pair) per t

  {
    const int k = tid;                    // 0..511 exactly once
    Ul2[k][0] = (k < NH) ? U[(size_t)h0 * NH + k] : 0.0f;
    Ul2[k][1] = (k < NH) ? U[(size_t)(h0 + 1) * NH + k] : 0.0f;
    const int t = tid >> 1;
    keyl[tid] = keys[4 * t + (tid & 1)];
  }
  const float bh0 = b_h[h0], bh1 = b_h[h0 + 1];
  const float bi0 = b_init[h0], bi1 = b_init[h0 + 1];
  __syncthreads();

  const int bk = (int)(blockIdx.x & (NBUCK - 1));
  const uint32_t bsize = (bk < (NBLK_B & (NBUCK - 1))) ? (NBLK_B / NBUCK + 1)
                                                       : (NBLK_B / NBUCK);

  for (int t = 0; t < TT; ++t) {
    const float* __restrict__ r_old = (t & 1) ? rbuf1 : rbuf0;
    float* __restrict__ r_new = (t & 1) ? rbuf0 : rbuf1;

    // wv prefetch (p0 epilogue operand) — hides under the dot
    float wv0 = 0.0f, wv1 = 0.0f;
    if (p == 0) {
      wv0 = wv[((size_t)t * NH + h0) * BB + b];
      wv1 = wv[((size_t)t * NH + h0 + 1) * BB + b];
    }

    float ps0, ps1;
    if (p == 0) panel_dot<9>(r_old, 0, b, Ul2, ps0, ps1);      // k 0..288
    else        panel_dot<7>(r_old, 288, b, Ul2, ps0, ps1);    // k 288..512 (pad +0)

    if (p == 1) {
      ps_lds[0][b] = ps0;
      ps_lds[1][b] = ps1;
      const uint32_t key0 = keyl[2 * t], key1 = keyl[2 * t + 1];
      u_lds[0][b] = jax_uniform(draw_bits(key0, key1, (uint32_t)(h0 * BB + b)));
      u_lds[1][b] = jax_uniform(draw_bits(key0, key1, (uint32_t)((h0 + 1) * BB + b)));
    }
    __syncthreads();

    if (p == 0) {
      float acc0 = ps0 + ps_lds[0][b];   // == (0+panel0)+panel1 of the reference
      float acc1 = ps1 + ps_lds[1][b];
      float pre0 = (wv0 + acc0) + ((t == 0) ? bi0 : bh0);
      float pre1 = (wv1 + acc1) + ((t == 0) ? bi1 : bh1);
      float pp0 = xla_sigmoid(pre0);
      float pp1 = xla_sigmoid(pre1);
      r_new[h0 * BB + b] = pp0;
      r_new[(h0 + 1) * BB + b] = pp1;
      out_r[(size_t)h0 * (TT * BB) + (size_t)t * BB + b] =
          (u_lds[0][b] < pp0) ? 1.0f : 0.0f;
      out_r[(size_t)(h0 + 1) * (TT * BB) + (size_t)t * BB + b] =
          (u_lds[1][b] < pp1) ? 1.0f : 0.0f;
    }

    if (t == TT - 1) break;   // dispatch-end fence covers the last writes

    // ---- bucketed grid barrier: one release fence, relaxed spin, one acquire ----
    __syncthreads();          // drains vmcnt: r_new/out_r stores reached L2
    if (tid == 0) {
      __builtin_amdgcn_fence(__ATOMIC_RELEASE, "agent");   // wbl2: push to L3
      uint32_t old = __hip_atomic_fetch_add(&bar[bk * 32], 1u,
                         __ATOMIC_RELAXED, __HIP_MEMORY_SCOPE_AGENT);
      if ((old % bsize) == bsize - 1u)
        __hip_atomic_fetch_add(&bar[NBUCK * 32], bsize,
                         __ATOMIC_RELAXED, __HIP_MEMORY_SCOPE_AGENT);
      const uint32_t target = (uint32_t)(t + 1) * (uint32_t)NBLK_B;
      while (__hip_atomic_load(&bar[NBUCK * 32], __ATOMIC_RELAXED,
                               __HIP_MEMORY_SCOPE_AGENT) < target)
        __builtin_amdgcn_s_sleep(8);
      __builtin_amdgcn_fence(__ATOMIC_ACQUIRE, "agent");   // inv: see fresh r_new
    }
    __syncthreads();
  }
}

// ---------------- Phase C: all visible steps; h read from out_r ----------------
// fmaf(w, h, s) == s + w*h bit-exactly because h in {0,1}.
#define IT_C 16   // 784/16 = 49 i-tiles
__global__ __launch_bounds__(256) void visible_big(
    const float* __restrict__ WT, const float* __restrict__ b_v,
    const uint32_t* __restrict__ keys, const float* __restrict__ hplane,
    float* __restrict__ out_v) {
#pragma clang fp contract(off)
  const int b = threadIdx.x;
  const int i0 = blockIdx.x * IT_C;
  const int t = blockIdx.y;
  const float* hcol = hplane + (size_t)t * BB + b;  // element k: hcol[k * TT*BB]

  float acc[IT_C];
#pragma unroll
  for (int r = 0; r < IT_C; ++r) acc[r] = 0.0f;

  const int pb[3] = {0, 288, 500};
#pragma unroll 1
  for (int p = 0; p < 2; ++p) {
    float ps[IT_C];
#pragma unroll
    for (int r = 0; r < IT_C; ++r) ps[r] = 0.0f;
    const int k0 = pb[p], k1 = pb[p + 1];
#pragma unroll 8
    for (int k = k0; k < k1; ++k) {
      float hh = hcol[(size_t)k * (TT * BB)];
#pragma unroll
      for (int r = 0; r < IT_C; ++r)
        ps[r] = __builtin_fmaf(WT[(size_t)(i0 + r) * NH + k], hh, ps[r]);
    }
#pragma unroll
    for (int r = 0; r < IT_C; ++r) acc[r] = acc[r] + ps[r];
  }

  const uint32_t key0 = keys[4 * t + 2], key1 = keys[4 * t + 3];
#pragma unroll
  for (int r = 0; r < IT_C; ++r) {
    const int i = i0 + r;
    float pre = acc[r] + b_v[i];
    float p = xla_sigmoid(pre);
    uint32_t j = (uint32_t)(i * BB + b);
    float u = jax_uniform(draw_bits(key0, key1, j));
    out_v[(size_t)i * (TT * BB) + (size_t)t * BB + b] = (u < p) ? 1.0f : 0.0f;
  }
}

extern "C" void kernel_launch(void* const* d_in, const int* in_sizes, int n_in,
                              void* d_out, int out_size, void* d_ws, size_t ws_size,
                              hipStream_t stream) {
  const float* v      = (const float*)d_in[0];
  const float* W      = (const float*)d_in[1];
  const float* U      = (const float*)d_in[2];
  const float* b_h    = (const float*)d_in[3];
  const float* b_v    = (const float*)d_in[4];
  const float* b_init = (const float*)d_in[5];

  float* out_v = (float*)d_out;                       // (784,256,256)
  float* out_r = out_v + (size_t)NV * TT * BB;        // (500,256,256)

  // WV for all t lives in the out_v region (131 MB <= 205 MB); phase C
  // overwrites out_v afterwards and never reads WV.
  float* wv = out_v;

  // ws layout: r0, r1 (padded to 512 rows), WT, keys, bar
  float* r0 = (float*)d_ws;
  float* r1 = r0 + (size_t)RPAD * BB;
  float* WT = r1 + (size_t)RPAD * BB;
  uint32_t* keys = (uint32_t*)(WT + (size_t)NV * NH);
  uint32_t* bar = keys + TT * 4;   // (NBUCK+1)*32 u32, 128B-spaced counters

  // zero r0 AND r1 fully: r_lag(0)=0, and pad rows (500..511) must be 0 finite
  hipMemsetAsync(r0, 0, (size_t)2 * RPAD * BB * sizeof(float), stream);
  hipMemsetAsync(bar, 0, (NBUCK + 1) * 32 * sizeof(uint32_t), stream);
  init_keys<<<1, 256, 0, stream>>>(keys);
  wt_kernel<<<NV, 256, 0, stream>>>(W, WT);

  dim3 gA(NH / HT_A, TT);
  wv_gemm<<<gA, 256, 0, stream>>>(v, W, wv);

  hidden_persist<<<NBLK_B, 512, 0, stream>>>(wv, U, b_h, b_init, keys,
                                             r0, r1, out_r, bar);

  dim3 gC(NV / IT_C, TT);
  visible_big<<<gC, 256, 0, stream>>>(WT, b_v, keys, out_r, out_v);
}

// Round 7
// 9301.601 us; speedup vs baseline: 1.6370x; 1.0299x over previous
//
#include <hip/hip_runtime.h>
#include <stdint.h>

// RTRBM CD-1: bit-exact replication of the JAX-CPU reference.
// KEY INSIGHT: the recurrence is independent per batch column b. No grid
// barriers/fences needed — one block per b-pair keeps r entirely in LDS.
// Phase A: WV2[bg][t][h][2] = (W @ v_t) (FMA exact: v binary), LDS-transposed
//          stores, staged in the out_v region of d_out.
// Phase B: hidden_cols — 128 blocks x 512 threads, thread h computes 2 b-columns,
//          U streamed from L2 (float4), r ping-pong in LDS, h out as packed bits.
// Phase E: expand bits -> out_r floats (coalesced).
// Phase C: all visible steps, one launch, h from out_r (FMA exact: h binary).
// Sizes: V=784, H=500, T=256, B=256. RNG: threefry partitionable.
// Eigen MT blocking (AVX no-FMA jaxlib): kc=288. K=784 -> [288,288,208]; K=500 -> [288,212].
#define NV 784
#define NH 500
#define TT 256
#define BB 256
#define NBG 128   // b-pairs

// ---------------- threefry2x32 (JAX PRNG), exact ----------------
__device__ __forceinline__ void tf2x32(uint32_t ks0, uint32_t ks1,
                                       uint32_t x0, uint32_t x1,
                                       uint32_t& y0, uint32_t& y1) {
  uint32_t ks2 = ks0 ^ ks1 ^ 0x1BD11BDAu;
  x0 += ks0; x1 += ks1;
#define TFROT(r) { x0 += x1; x1 = (x1 << (r)) | (x1 >> (32 - (r))); x1 ^= x0; }
  TFROT(13) TFROT(15) TFROT(26) TFROT(6)
  x0 += ks1; x1 += ks2 + 1u;
  TFROT(17) TFROT(29) TFROT(16) TFROT(24)
  x0 += ks2; x1 += ks0 + 2u;
  TFROT(13) TFROT(15) TFROT(26) TFROT(6)
  x0 += ks0; x1 += ks1 + 3u;
  TFROT(17) TFROT(29) TFROT(16) TFROT(24)
  x0 += ks1; x1 += ks2 + 4u;
  TFROT(13) TFROT(15) TFROT(26) TFROT(6)
  x0 += ks2; x1 += ks0 + 5u;
#undef TFROT
  y0 = x0; y1 = x1;
}

__device__ __forceinline__ float jax_uniform(uint32_t bits) {
#pragma clang fp contract(off)
  float f = __uint_as_float((bits >> 9) | 0x3F800000u);
  return f - 1.0f;
}

// PARTITIONABLE random_bits, 32-bit: bits[j] = y0 ^ y1 of threefry(key; 0, j)
__device__ __forceinline__ uint32_t draw_bits(uint32_t k0, uint32_t k1,
                                              uint32_t j) {
  uint32_t y0, y1;
  tf2x32(k0, k1, 0u, j, y0, y1);
  return y0 ^ y1;
}

// ---------------- XLA CPU exp (Cephes/Eigen poly, no FMA) ----------------
__device__ __forceinline__ float xla_expf(float x) {
#pragma clang fp contract(off)
  float xc = fminf(fmaxf(x, -88.3762626647949f), 88.3762626647950f);
  float fx = floorf(xc * 1.44269504088896341f + 0.5f);
  float tmp = 0.693359375f * fx;
  float z = -2.12194440e-4f * fx;
  float xr = xc - tmp;
  xr = xr - z;
  z = xr * xr;
  float y = xr * 1.9875691500e-4f + 1.3981999507e-3f;
  y = y * xr + 8.3334519073e-3f;
  y = y * xr + 4.1665795894e-2f;
  y = y * xr + 1.6666665459e-1f;
  y = y * xr + 5.0000001201e-1f;
  y = y * z + xr;
  y = 1.0f + y;
  int e = (int)fx;
  float pow2 = __int_as_float((uint32_t)(e + 127) << 23);
  return y * pow2;
}

__device__ __forceinline__ float xla_sigmoid(float x) {
#pragma clang fp contract(off)
  float e = xla_expf(-x);
  float d = 1.0f + e;
  return 1.0f / d;
}

// ---------------- key derivation (PARTITIONABLE split) ----------------
__global__ void init_keys(uint32_t* __restrict__ keys /* [256][4] */) {
  int t = threadIdx.x;
  if (t >= TT) return;
  uint32_t kt0, kt1;
  tf2x32(0u, 123u, 0u, (uint32_t)t, kt0, kt1);
  uint32_t a0, a1, b0, b1;
  tf2x32(kt0, kt1, 0u, 0u, a0, a1);  // k1 (hidden)
  tf2x32(kt0, kt1, 0u, 1u, b0, b1);  // k2 (visible)
  keys[4 * t + 0] = a0;
  keys[4 * t + 1] = a1;
  keys[4 * t + 2] = b0;
  keys[4 * t + 3] = b1;
}

// ---------------- W transpose: WT[i][k] = W[k][i] ----------------
__global__ __launch_bounds__(256) void wt_kernel(const float* __restrict__ W,
                                                 float* __restrict__ WT) {
  const int i = blockIdx.x;           // 0..783
  for (int k = threadIdx.x; k < NH; k += 256)
    WT[(size_t)i * NH + k] = W[(size_t)k * NV + i];
}

// ---------------- Phase A: WV2[bg][t][h][2] = (W @ v_t)[h][b] ----------------
// fmaf(w, x, s) == s + w*x bit-exactly because x in {0,1} (w*x exact).
#define HT_A 25   // 500/25 = 20 blocks per t
__global__ __launch_bounds__(256) void wv_gemm(
    const float* __restrict__ v, const float* __restrict__ W,
    float* __restrict__ wv2) {
#pragma clang fp contract(off)
  const int b = threadIdx.x;
  const int h0 = blockIdx.x * HT_A;
  const int t = blockIdx.y;
  const float* vcol = v + (size_t)t * BB + b;   // element k: vcol[k * TT*BB]

  float acc[HT_A];
#pragma unroll
  for (int r = 0; r < HT_A; ++r) acc[r] = 0.0f;

  const int pb[4] = {0, 288, 576, 784};   // kc=288 panels
#pragma unroll 1
  for (int p = 0; p < 3; ++p) {
    float ps[HT_A];
#pragma unroll
    for (int r = 0; r < HT_A; ++r) ps[r] = 0.0f;
    const int k0 = pb[p], k1 = pb[p + 1];
#pragma unroll 16
    for (int k = k0; k < k1; ++k) {
      float x = vcol[(size_t)k * (TT * BB)];
#pragma unroll
      for (int r = 0; r < HT_A; ++r)
        ps[r] = __builtin_fmaf(W[(size_t)(h0 + r) * NV + k], x, ps[r]);
    }
#pragma unroll
    for (int r = 0; r < HT_A; ++r) acc[r] = acc[r] + ps[r];
  }

  // LDS transpose so stores are h-contiguous runs of 50 floats per bg
  __shared__ float al[HT_A][BB];
#pragma unroll
  for (int r = 0; r < HT_A; ++r) al[r][b] = acc[r];
  __syncthreads();

  // write 50-float runs: wv2[bg][t][h0*2 .. h0*2+49]
  const int tid = b;
  const int sub = tid / 50;       // 0..4 (5 bg per iter), tid<250 active
  const int idx = tid % 50;       // (h-r, j) pair index: h = h0 + idx/2, j = idx&1
#pragma unroll 1
  for (int it = 0; it < 26; ++it) {
    const int bg = it * 5 + sub;
    if (tid < 250 && bg < NBG) {
      wv2[((size_t)bg * TT + t) * 1024 + h0 * 2 + idx] =
          al[idx >> 1][2 * bg + (idx & 1)];
    }
  }
}

// ---------------- Phase B: per-b-pair recurrence, r in LDS, no barriers ----------------
__global__ __launch_bounds__(512) void hidden_cols(
    const float* __restrict__ U, const float* __restrict__ b_h,
    const float* __restrict__ b_init, const uint32_t* __restrict__ keys,
    const float* __restrict__ wv2, uint32_t* __restrict__ hbw) {
#pragma clang fp contract(off)
  const int tid = threadIdx.x;        // = h (500 active, 512 padded)
  const int bg = blockIdx.x;
  const int b0 = 2 * bg;
  const int h = tid;
  const int hs = (h < NH) ? h : 0;    // safe row for padding lanes

  __shared__ float rA[512][2];        // r ping-pong, [k][b-pair]
  __shared__ float rB[512][2];
  __shared__ uint32_t keyl[2 * TT];

  keyl[tid] = keys[4 * (tid >> 1) + (tid & 1)];   // k1 pairs for all t
  rA[tid][0] = 0.0f;  rA[tid][1] = 0.0f;          // r_lag(0) = 0
  const float bh = b_h[hs], bi = b_init[hs];
  const float* __restrict__ Urow = U + (size_t)hs * NH;   // 16B-aligned (2000B rows)
  __syncthreads();

#pragma unroll 1
  for (int t = 0; t < TT; ++t) {
    const float* __restrict__ ro = (t & 1) ? &rB[0][0] : &rA[0][0];
    float* __restrict__ rn = (t & 1) ? &rA[0][0] : &rB[0][0];

    // prefetch the WV pair (contiguous, coalesced)
    const float2 wvp =
        *(const float2*)&wv2[((size_t)bg * TT + t) * 1024 + h * 2];

    // U @ r_lag for 2 columns: mul-then-add (no FMA: r arbitrary),
    // strict ascending k, Eigen panels [0,288) and [288,500).
    float p0a = 0.0f, p0b = 0.0f;
#pragma unroll 4
    for (int c = 0; c < 72; ++c) {          // panel 0: k = 0..287
      const int k = 4 * c;
      const float4 u4 = *(const float4*)(Urow + k);
      const float4 rx = *(const float4*)(ro + 2 * k);
      const float4 ry = *(const float4*)(ro + 2 * k + 4);
      p0a = p0a + u4.x * rx.x;  p0b = p0b + u4.x * rx.y;
      p0a = p0a + u4.y * rx.z;  p0b = p0b + u4.y * rx.w;
      p0a = p0a + u4.z * ry.x;  p0b = p0b + u4.z * ry.y;
      p0a = p0a + u4.w * ry.z;  p0b = p0b + u4.w * ry.w;
    }
    float p1a = 0.0f, p1b = 0.0f;
#pragma unroll 4
    for (int c = 0; c < 53; ++c) {          // panel 1: k = 288..499
      const int k = 288 + 4 * c;
      const float4 u4 = *(const float4*)(Urow + k);
      const float4 rx = *(const float4*)(ro + 2 * k);
      const float4 ry = *(const float4*)(ro + 2 * k + 4);
      p1a = p1a + u4.x * rx.x;  p1b = p1b + u4.x * rx.y;
      p1a = p1a + u4.y * rx.z;  p1b = p1b + u4.y * rx.w;
      p1a = p1a + u4.z * ry.x;  p1b = p1b + u4.z * ry.y;
      p1a = p1a + u4.w * ry.z;  p1b = p1b + u4.w * ry.w;
    }

    const float bias = (t == 0) ? bi : bh;
    const float pre0 = (wvp.x + (p0a + p1a)) + bias;   // reference order
    const float pre1 = (wvp.y + (p0b + p1b)) + bias;
    const float pp0 = xla_sigmoid(pre0);
    const float pp1 = xla_sigmoid(pre1);

    const uint32_t key0 = keyl[2 * t], key1 = keyl[2 * t + 1];
    const float u0 = jax_uniform(draw_bits(key0, key1, (uint32_t)(h * BB + b0)));
    const float u1 = jax_uniform(draw_bits(key0, key1, (uint32_t)(h * BB + b0 + 1)));
    const bool hm0 = u0 < pp0;
    const bool hm1 = u1 < pp1;

    // pack h samples: 64-lane ballot over h within the wave
    const unsigned long long m0 = __ballot(hm0);
    const unsigned long long m1 = __ballot(hm1);
    const int lh = h & 63;
    if (lh == 0) {
      uint2 w; w.x = (uint32_t)m0; w.y = (uint32_t)m1;
      *(uint2*)&hbw[(size_t)(h >> 5) * (TT * BB) + (size_t)t * BB + b0] = w;
    }
    if (lh == 32) {
      uint2 w; w.x = (uint32_t)(m0 >> 32); w.y = (uint32_t)(m1 >> 32);
      *(uint2*)&hbw[(size_t)(h >> 5) * (TT * BB) + (size_t)t * BB + b0] = w;
    }

    // write r_new (buffer differs from ro; safe: t-1's readers of this
    // buffer all finished at the previous __syncthreads)
    rn[h * 2] = pp0;
    rn[h * 2 + 1] = pp1;
    __syncthreads();
  }
}

// ---------------- Phase E: expand packed h bits -> out_r floats ----------------
__global__ __launch_bounds__(256) void expand_r(
    const uint32_t* __restrict__ hbw, float* __restrict__ out_r) {
  const int h = blockIdx.x;           // 0..499
  const int b = threadIdx.x;
  const uint32_t sh = (uint32_t)(h & 31);
  const uint32_t* src = hbw + (size_t)(h >> 5) * (TT * BB);
  float* dst = out_r + (size_t)h * (TT * BB);
#pragma unroll 4
  for (int t = 0; t < TT; ++t) {
    uint32_t w = src[t * BB + b];
    dst[t * BB + b] = (float)((w >> sh) & 1u);
  }
}

// ---------------- Phase C: all visible steps; h read from out_r ----------------
// fmaf(w, h, s) == s + w*h bit-exactly because h in {0,1}.
#define IT_C 16   // 784/16 = 49 i-tiles
__global__ __launch_bounds__(256) void visible_big(
    const float* __restrict__ WT, const float* __restrict__ b_v,
    const uint32_t* __restrict__ keys, const float* __restrict__ hplane,
    float* __restrict__ out_v) {
#pragma clang fp contract(off)
  const int b = threadIdx.x;
  const int i0 = blockIdx.x * IT_C;
  const int t = blockIdx.y;
  const float* hcol = hplane + (size_t)t * BB + b;  // element k: hcol[k * TT*BB]

  float acc[IT_C];
#pragma unroll
  for (int r = 0; r < IT_C; ++r) acc[r] = 0.0f;

  const int pb[3] = {0, 288, 500};
#pragma unroll 1
  for (int p = 0; p < 2; ++p) {
    float ps[IT_C];
#pragma unroll
    for (int r = 0; r < IT_C; ++r) ps[r] = 0.0f;
    const int k0 = pb[p], k1 = pb[p + 1];
#pragma unroll 8
    for (int k = k0; k < k1; ++k) {
      float hh = hcol[(size_t)k * (TT * BB)];
#pragma unroll
      for (int r = 0; r < IT_C; ++r)
        ps[r] = __builtin_fmaf(WT[(size_t)(i0 + r) * NH + k], hh, ps[r]);
    }
#pragma unroll
    for (int r = 0; r < IT_C; ++r) acc[r] = acc[r] + ps[r];
  }

  const uint32_t key0 = keys[4 * t + 2], key1 = keys[4 * t + 3];
#pragma unroll
  for (int r = 0; r < IT_C; ++r) {
    const int i = i0 + r;
    float pre = acc[r] + b_v[i];
    float p = xla_sigmoid(pre);
    uint32_t j = (uint32_t)(i * BB + b);
    float u = jax_uniform(draw_bits(key0, key1, j));
    out_v[(size_t)i * (TT * BB) + (size_t)t * BB + b] = (u < p) ? 1.0f : 0.0f;
  }
}

extern "C" void kernel_launch(void* const* d_in, const int* in_sizes, int n_in,
                              void* d_out, int out_size, void* d_ws, size_t ws_size,
                              hipStream_t stream) {
  const float* v      = (const float*)d_in[0];
  const float* W      = (const float*)d_in[1];
  const float* U      = (const float*)d_in[2];
  const float* b_h    = (const float*)d_in[3];
  const float* b_v    = (const float*)d_in[4];
  const float* b_init = (const float*)d_in[5];

  float* out_v = (float*)d_out;                       // (784,256,256) = 205.5 MB
  float* out_r = out_v + (size_t)NV * TT * BB;        // (500,256,256) = 131 MB

  // Scratch staged inside the out_v region (overwritten by phase C at the end):
  //   wv2: [128][256][512][2] f32 = 134.2 MB
  //   hbw: [16][256][256] u32    = 4 MB
  float* wv2 = out_v;
  uint32_t* hbw = (uint32_t*)(out_v + (size_t)NBG * TT * 1024);

  // ws: WT (1.57 MB) + keys (4 KB)
  float* WT = (float*)d_ws;
  uint32_t* keys = (uint32_t*)(WT + (size_t)NV * NH);

  init_keys<<<1, 256, 0, stream>>>(keys);
  wt_kernel<<<NV, 256, 0, stream>>>(W, WT);

  dim3 gA(NH / HT_A, TT);
  wv_gemm<<<gA, 256, 0, stream>>>(v, W, wv2);

  hidden_cols<<<NBG, 512, 0, stream>>>(U, b_h, b_init, keys, wv2, hbw);

  expand_r<<<NH, 256, 0, stream>>>(hbw, out_r);

  dim3 gC(NV / IT_C, TT);
  visible_big<<<gC, 256, 0, stream>>>(WT, b_v, keys, out_r, out_v);
}